// Round 6
// baseline (5462.814 us; speedup 1.0000x reference)
//
#include <hip/hip_runtime.h>

namespace {

constexpr int BATCH = 32768;
constexpr int TSTEPS = 28;

__device__ __forceinline__ float bpermf(int idx, float v) {
    return __int_as_float(__builtin_amdgcn_ds_bpermute(idx, __float_as_int(v)));
}

// DPP quad_perm shuffles (VALU-pipe, full rate)
constexpr int XOR1 = 0xB1;  // quad_perm [1,0,3,2]  -> lane ^ 1
constexpr int XOR2 = 0x4E;  // quad_perm [2,3,0,1]  -> lane ^ 2

template <int CTRL>
__device__ __forceinline__ float dppf(float v) {
    return __int_as_float(__builtin_amdgcn_mov_dpp(__float_as_int(v), CTRL, 0xF, 0xF, true));
}

__device__ __forceinline__ float exp2f_fast(float x) { return __builtin_amdgcn_exp2f(x); }
__device__ __forceinline__ float rcpf_fast(float x) { return __builtin_amdgcn_rcpf(x); }

__device__ __forceinline__ float tanhf_fast(float x) {
    float e = exp2f_fast(x * 2.885390081777927f);
    return 1.0f - 2.0f * rcpf_fast(1.0f + e);
}
__device__ __forceinline__ float sigmf_fast(float x) {
    float e = exp2f_fast(x * -1.4426950408889634f);
    return rcpf_fast(1.0f + e);
}

// 32 lanes per batch element (r5 redesign: fit TRUE register demand under the
// backend's 128-VGPR budget instead of fighting spills):
//   q = lane bits {0,1} : col-block (cols 8q..8q+7), DPP-quad reduce dimension
//   p = lane bits {2,4} : row-block (rows 4p..4p+3)
//   e = lane bit  {5}   : element-within-wave (2 per wave)
// Lane (p,q) holds rows 4p+(j^q), cols 8q..8q+7 of W1/W2 (4x8 = 32 regs each).
// Row perm j^q makes the XOR reduce-scatter placement-free: after (xor2, xor1)
// P[0] = full sum of row 4p+q -> each lane owns component cmp = 4p+q = lane&31.
//
// GRU weights in LDS, XOR-swizzled: store col c of row r at c ^ (r & 28)
// (r bits 2-4 == p) -> per-instr reads are exactly 4-way (b128 minimum), vs
// 8-way at r5's stride-36 (rows step 8*36 words == 0 mod 32).
//
// waves_per_eu(4,4): pin the allocator's occupancy target to 4 waves/EU
// (128-reg budget). With 24 KB LDS the LDS-derived target would be 6/EU ->
// ~85-reg budget -> spills (the r1-r5 disease).
__global__ __launch_bounds__(256) __attribute__((amdgpu_waves_per_eu(4, 4)))
void node_kernel(
    const float* __restrict__ g_inputs, const float* __restrict__ g_h0,
    const float* __restrict__ g_Wih, const float* __restrict__ g_Whh,
    const float* __restrict__ g_bih, const float* __restrict__ g_bhh,
    const float* __restrict__ g_W1, const float* __restrict__ g_b1,
    const float* __restrict__ g_W2, const float* __restrict__ g_b2,
    float* __restrict__ g_out)
{
    __shared__ __align__(16) float sWih[96 * 32];
    __shared__ __align__(16) float sWhh[96 * 32];

    const int tid = threadIdx.x;
    for (int i = tid; i < 96 * 32; i += 256) {
        int r = i >> 5, c = i & 31;
        int cs = c ^ (r & 28);   // XOR-swizzle on col bits 2-4
        sWih[r * 32 + cs] = g_Wih[i];
        sWhh[r * 32 + cs] = g_Whh[i];
    }
    __syncthreads();

    const int lane = tid & 63;
    const int wid = tid >> 6;
    const int q = lane & 3;
    const int p = (lane >> 2) & 7;
    const int e = lane >> 5;
    const int elem = blockIdx.x * 8 + wid * 2 + e;
    const int cmp = (p << 2) | q;          // owned component

    // bpermute byte-indices: component 8q+n owned by lane (n&3) | (2q+(n>>2))<<2
    int idx[8];
    {
        const int ebit = e << 5;
        #pragma unroll
        for (int n = 0; n < 8; ++n) {
            int sl = (n & 3) | ((2 * q + (n >> 2)) << 2) | ebit;
            idx[n] = sl << 2;
        }
    }

    // ODE MLP weights in registers: 4x8 block per lane, rows 4p+(j^q)
    float w1[4][8], w2[4][8];
    #pragma unroll
    for (int j = 0; j < 4; ++j) {
        const int row = 4 * p + (j ^ q);
        float4 a = *reinterpret_cast<const float4*>(&g_W1[row * 32 + 8 * q]);
        float4 b = *reinterpret_cast<const float4*>(&g_W1[row * 32 + 8 * q + 4]);
        w1[j][0] = a.x; w1[j][1] = a.y; w1[j][2] = a.z; w1[j][3] = a.w;
        w1[j][4] = b.x; w1[j][5] = b.y; w1[j][6] = b.z; w1[j][7] = b.w;
        float4 c = *reinterpret_cast<const float4*>(&g_W2[row * 32 + 8 * q]);
        float4 d = *reinterpret_cast<const float4*>(&g_W2[row * 32 + 8 * q + 4]);
        w2[j][0] = c.x; w2[j][1] = c.y; w2[j][2] = c.z; w2[j][3] = c.w;
        w2[j][4] = d.x; w2[j][5] = d.y; w2[j][6] = d.z; w2[j][7] = d.w;
    }

    const float b1o = g_b1[cmp];
    const float b2o = g_b2[cmp];
    const float br  = g_bih[cmp] + g_bhh[cmp];
    const float bz  = g_bih[32 + cmp] + g_bhh[32 + cmp];
    const float bin = g_bih[64 + cmp];
    const float bhn = g_bhh[64 + cmp];

    float y = g_h0[(size_t)elem * 32 + cmp];   // owned component of hidden state

    auto gather8 = [&](float v, float (&in)[8]) {
        #pragma unroll
        for (int n = 0; n < 8; ++n) in[n] = bpermf(idx[n], v);
    };

    // XOR reduce-scatter over q: returns full sum of row 4p+q
    auto reduceP = [&](float (&P)[4]) -> float {
        P[0] += dppf<XOR2>(P[2]);
        P[1] += dppf<XOR2>(P[3]);
        P[0] += dppf<XOR1>(P[1]);
        return P[0];
    };

    auto layer = [&](const float (&w)[4][8], const float (&in)[8]) -> float {
        float P[4];
        #pragma unroll
        for (int j = 0; j < 4; ++j) {
            float s = w[j][0] * in[0];
            #pragma unroll
            for (int cc = 1; cc < 8; ++cc) s = fmaf(w[j][cc], in[cc], s);
            P[j] = s;
        }
        return reduceP(P);
    };

    auto rhs = [&](float v) -> float {
        float in[8];
        gather8(v, in);
        float t = tanhf_fast(layer(w1, in) + b1o);
        gather8(t, in);
        return layer(w2, in) + b2o;
    };

    auto rk4 = [&](float dt) {
        const float hdt = 0.5f * dt;
        const float sdt = dt * (1.0f / 6.0f);
        #pragma unroll 1
        for (int s = 0; s < 10; ++s) {
            float k1 = rhs(y);
            float a = k1;
            float k = rhs(fmaf(hdt, k1, y));
            a = fmaf(2.0f, k, a);
            k = rhs(fmaf(hdt, k, y));
            a = fmaf(2.0f, k, a);
            k = rhs(fmaf(dt, k, y));
            a += k;
            y = fmaf(sdt, a, y);
        }
    };

    // One gate's (Wih.x + Whh.h) dot, swizzled b128 reads; returns owned comp.
    auto gate_dot2 = [&](int gofs, const float (&xin)[8], const float (&hin)[8]) -> float {
        float P[4];
        #pragma unroll
        for (int j = 0; j < 4; ++j) {
            const int row = gofs + 4 * p + (j ^ q);
            const int swz = row & 28;
            const int c0 = (8 * q) ^ swz;
            const int c1 = (8 * q + 4) ^ swz;
            const float* wi = &sWih[row * 32];
            const float* wh = &sWhh[row * 32];
            float4 a0 = *reinterpret_cast<const float4*>(wi + c0);
            float4 a1 = *reinterpret_cast<const float4*>(wi + c1);
            float4 h0v = *reinterpret_cast<const float4*>(wh + c0);
            float4 h1v = *reinterpret_cast<const float4*>(wh + c1);
            float s;
            s = a0.x * xin[0];
            s = fmaf(a0.y, xin[1], s);
            s = fmaf(a0.z, xin[2], s);
            s = fmaf(a0.w, xin[3], s);
            s = fmaf(a1.x, xin[4], s);
            s = fmaf(a1.y, xin[5], s);
            s = fmaf(a1.z, xin[6], s);
            s = fmaf(a1.w, xin[7], s);
            s = fmaf(h0v.x, hin[0], s);
            s = fmaf(h0v.y, hin[1], s);
            s = fmaf(h0v.z, hin[2], s);
            s = fmaf(h0v.w, hin[3], s);
            s = fmaf(h1v.x, hin[4], s);
            s = fmaf(h1v.y, hin[5], s);
            s = fmaf(h1v.z, hin[6], s);
            s = fmaf(h1v.w, hin[7], s);
            P[j] = s;
        }
        return reduceP(P);
    };

    auto gate_dot1 = [&](const float* smat, int gofs, const float (&vin)[8]) -> float {
        float P[4];
        #pragma unroll
        for (int j = 0; j < 4; ++j) {
            const int row = gofs + 4 * p + (j ^ q);
            const int swz = row & 28;
            const int c0 = (8 * q) ^ swz;
            const int c1 = (8 * q + 4) ^ swz;
            const float* wr = &smat[row * 32];
            float4 a0 = *reinterpret_cast<const float4*>(wr + c0);
            float4 a1 = *reinterpret_cast<const float4*>(wr + c1);
            float s;
            s = a0.x * vin[0];
            s = fmaf(a0.y, vin[1], s);
            s = fmaf(a0.z, vin[2], s);
            s = fmaf(a0.w, vin[3], s);
            s = fmaf(a1.x, vin[4], s);
            s = fmaf(a1.y, vin[5], s);
            s = fmaf(a1.z, vin[6], s);
            s = fmaf(a1.w, vin[7], s);
            P[j] = s;
        }
        return reduceP(P);
    };

    // Sequential-gate GRU with sched_barrier fences (pressure insurance)
    auto gru = [&](int t) {
        float xin[8];
        {
            const float* xp = &g_inputs[((size_t)elem * TSTEPS + t) * 32 + 8 * q];
            float4 xa = *reinterpret_cast<const float4*>(xp);
            float4 xb = *reinterpret_cast<const float4*>(xp + 4);
            xin[0] = xa.x; xin[1] = xa.y; xin[2] = xa.z; xin[3] = xa.w;
            xin[4] = xb.x; xin[5] = xb.y; xin[6] = xb.z; xin[7] = xb.w;
        }
        float hin[8];
        gather8(y, hin);
        __builtin_amdgcn_sched_barrier(0);

        float r = sigmf_fast(gate_dot2(0, xin, hin) + br);
        __builtin_amdgcn_sched_barrier(0);
        float z = sigmf_fast(gate_dot2(32, xin, hin) + bz);
        __builtin_amdgcn_sched_barrier(0);
        float nx = gate_dot1(sWih, 64, xin);
        __builtin_amdgcn_sched_barrier(0);
        float nh = gate_dot1(sWhh, 64, hin);
        __builtin_amdgcn_sched_barrier(0);
        float n = tanhf_fast(nx + bin + r * (nh + bhn));
        y = n + z * (y - n);
    };

    // initial integration over [0,1]
    rk4(0.1f);
    #pragma unroll 1
    for (int t = 0; t < TSTEPS - 1; ++t) {
        gru(t);
        rk4(0.1f);
    }
    gru(TSTEPS - 1);
    g_out[(size_t)elem * 32 + cmp] = fmaxf(y, 0.f);              // h_start (relu)
    rk4(1.4f);                                                    // span 14 -> dt 1.4
    g_out[(size_t)BATCH * 32 + (size_t)elem * 32 + cmp] = fmaxf(y, 0.f);  // h_end
}

}  // namespace

extern "C" void kernel_launch(void* const* d_in, const int* in_sizes, int n_in,
                              void* d_out, int out_size, void* d_ws, size_t ws_size,
                              hipStream_t stream) {
    (void)in_sizes; (void)n_in; (void)out_size; (void)d_ws; (void)ws_size;
    const float* inputs = (const float*)d_in[0];
    const float* h0     = (const float*)d_in[1];
    const float* Wih    = (const float*)d_in[2];
    const float* Whh    = (const float*)d_in[3];
    const float* bih    = (const float*)d_in[4];
    const float* bhh    = (const float*)d_in[5];
    const float* W1     = (const float*)d_in[6];
    const float* b1     = (const float*)d_in[7];
    const float* W2     = (const float*)d_in[8];
    const float* b2     = (const float*)d_in[9];
    float* out = (float*)d_out;

    dim3 grid(BATCH / 8);    // 8 elements per 256-thread block (32 lanes/element)
    dim3 block(256);
    hipLaunchKernelGGL(node_kernel, grid, block, 0, stream,
                       inputs, h0, Wih, Whh, bih, bhh, W1, b1, W2, b2, out);
}

// Round 8
// 4039.094 us; speedup vs baseline: 1.3525x; 1.3525x over previous
//
#include <hip/hip_runtime.h>

namespace {

constexpr int BATCH = 32768;
constexpr int TSTEPS = 28;

__device__ __forceinline__ float bpermf(int idx, float v) {
    return __int_as_float(__builtin_amdgcn_ds_bpermute(idx, __float_as_int(v)));
}

// DPP quad_perm shuffles (VALU-pipe, full rate)
constexpr int XOR1 = 0xB1;  // quad_perm [1,0,3,2]  -> lane ^ 1
constexpr int XOR2 = 0x4E;  // quad_perm [2,3,0,1]  -> lane ^ 2

template <int CTRL>
__device__ __forceinline__ float dppf(float v) {
    return __int_as_float(__builtin_amdgcn_mov_dpp(__float_as_int(v), CTRL, 0xF, 0xF, true));
}

__device__ __forceinline__ float exp2f_fast(float x) { return __builtin_amdgcn_exp2f(x); }
__device__ __forceinline__ float rcpf_fast(float x) { return __builtin_amdgcn_rcpf(x); }

__device__ __forceinline__ float tanhf_fast(float x) {
    float e = exp2f_fast(x * 2.885390081777927f);
    return 1.0f - 2.0f * rcpf_fast(1.0f + e);
}
__device__ __forceinline__ float sigmf_fast(float x) {
    float e = exp2f_fast(x * -1.4426950408889634f);
    return rcpf_fast(1.0f + e);
}

// 32 lanes per batch element; layout verified correct in r6 (absmax 0.03125):
//   q = lane bits {0,1} : col-block (cols 8q..8q+7), DPP-quad reduce dimension
//   p = lane bits {2,4} : row-block (rows 4p..4p+3)
//   e = lane bit  {5}   : element-within-wave (2 per wave)
// Lane (p,q) holds rows 4p+(j^q), cols 8q..8q+7 of W1/W2 (4x8 = 32 regs each).
// Row perm j^q makes the XOR reduce-scatter placement-free: after (xor2, xor1)
// P[0] = full sum of row 4p+q -> each lane owns component cmp = 4p+q = lane&31.
//
// GRU weights in LDS, XOR-swizzled (store col c of row r at c ^ (r & 28)):
// r6 confirmed SQ_LDS_BANK_CONFLICT == 0 with this scheme.
//
// Register-budget forensics (r1-r6): the backend's VGPR cap tracks the
// occupancy attribute in WAVE32 GRANULES: launch_bounds(256,2)/waves_per_eu(2,2)
// -> 512/4 = 128 regs; waves_per_eu(4,4) -> 512/8 = 64 regs (r6's disaster).
// launch_bounds(256,2) is the one config that reliably yields 128. This
// layout's true demand is ~105 regs -> fits under 128, genuinely spill-free.
__global__ __launch_bounds__(256, 2)
void node_kernel(
    const float* __restrict__ g_inputs, const float* __restrict__ g_h0,
    const float* __restrict__ g_Wih, const float* __restrict__ g_Whh,
    const float* __restrict__ g_bih, const float* __restrict__ g_bhh,
    const float* __restrict__ g_W1, const float* __restrict__ g_b1,
    const float* __restrict__ g_W2, const float* __restrict__ g_b2,
    float* __restrict__ g_out)
{
    __shared__ __align__(16) float sWih[96 * 32];
    __shared__ __align__(16) float sWhh[96 * 32];

    const int tid = threadIdx.x;
    for (int i = tid; i < 96 * 32; i += 256) {
        int r = i >> 5, c = i & 31;
        int cs = c ^ (r & 28);   // XOR-swizzle on col bits 2-4
        sWih[r * 32 + cs] = g_Wih[i];
        sWhh[r * 32 + cs] = g_Whh[i];
    }
    __syncthreads();

    const int lane = tid & 63;
    const int wid = tid >> 6;
    const int q = lane & 3;
    const int p = (lane >> 2) & 7;
    const int e = lane >> 5;
    const int elem = blockIdx.x * 8 + wid * 2 + e;
    const int cmp = (p << 2) | q;          // owned component

    // bpermute byte-indices: component 8q+n owned by lane (n&3) | (2q+(n>>2))<<2
    int idx[8];
    {
        const int ebit = e << 5;
        #pragma unroll
        for (int n = 0; n < 8; ++n) {
            int sl = (n & 3) | ((2 * q + (n >> 2)) << 2) | ebit;
            idx[n] = sl << 2;
        }
    }

    // ODE MLP weights in registers: 4x8 block per lane, rows 4p+(j^q)
    float w1[4][8], w2[4][8];
    #pragma unroll
    for (int j = 0; j < 4; ++j) {
        const int row = 4 * p + (j ^ q);
        float4 a = *reinterpret_cast<const float4*>(&g_W1[row * 32 + 8 * q]);
        float4 b = *reinterpret_cast<const float4*>(&g_W1[row * 32 + 8 * q + 4]);
        w1[j][0] = a.x; w1[j][1] = a.y; w1[j][2] = a.z; w1[j][3] = a.w;
        w1[j][4] = b.x; w1[j][5] = b.y; w1[j][6] = b.z; w1[j][7] = b.w;
        float4 c = *reinterpret_cast<const float4*>(&g_W2[row * 32 + 8 * q]);
        float4 d = *reinterpret_cast<const float4*>(&g_W2[row * 32 + 8 * q + 4]);
        w2[j][0] = c.x; w2[j][1] = c.y; w2[j][2] = c.z; w2[j][3] = c.w;
        w2[j][4] = d.x; w2[j][5] = d.y; w2[j][6] = d.z; w2[j][7] = d.w;
    }

    const float b1o = g_b1[cmp];
    const float b2o = g_b2[cmp];
    const float br  = g_bih[cmp] + g_bhh[cmp];
    const float bz  = g_bih[32 + cmp] + g_bhh[32 + cmp];
    const float bin = g_bih[64 + cmp];
    const float bhn = g_bhh[64 + cmp];

    float y = g_h0[(size_t)elem * 32 + cmp];   // owned component of hidden state

    auto gather8 = [&](float v, float (&in)[8]) {
        #pragma unroll
        for (int n = 0; n < 8; ++n) in[n] = bpermf(idx[n], v);
    };

    // XOR reduce-scatter over q: returns full sum of row 4p+q
    auto reduceP = [&](float (&P)[4]) -> float {
        P[0] += dppf<XOR2>(P[2]);
        P[1] += dppf<XOR2>(P[3]);
        P[0] += dppf<XOR1>(P[1]);
        return P[0];
    };

    auto layer = [&](const float (&w)[4][8], const float (&in)[8]) -> float {
        float P[4];
        #pragma unroll
        for (int j = 0; j < 4; ++j) {
            float s = w[j][0] * in[0];
            #pragma unroll
            for (int cc = 1; cc < 8; ++cc) s = fmaf(w[j][cc], in[cc], s);
            P[j] = s;
        }
        return reduceP(P);
    };

    auto rhs = [&](float v) -> float {
        float in[8];
        gather8(v, in);
        float t = tanhf_fast(layer(w1, in) + b1o);
        gather8(t, in);
        return layer(w2, in) + b2o;
    };

    auto rk4 = [&](float dt) {
        const float hdt = 0.5f * dt;
        const float sdt = dt * (1.0f / 6.0f);
        #pragma unroll 1
        for (int s = 0; s < 10; ++s) {
            float k1 = rhs(y);
            float a = k1;
            float k = rhs(fmaf(hdt, k1, y));
            a = fmaf(2.0f, k, a);
            k = rhs(fmaf(hdt, k, y));
            a = fmaf(2.0f, k, a);
            k = rhs(fmaf(dt, k, y));
            a += k;
            y = fmaf(sdt, a, y);
        }
    };

    // One gate's (Wih.x + Whh.h) dot, swizzled b128 reads; returns owned comp.
    auto gate_dot2 = [&](int gofs, const float (&xin)[8], const float (&hin)[8]) -> float {
        float P[4];
        #pragma unroll
        for (int j = 0; j < 4; ++j) {
            const int row = gofs + 4 * p + (j ^ q);
            const int swz = row & 28;
            const int c0 = (8 * q) ^ swz;
            const int c1 = (8 * q + 4) ^ swz;
            const float* wi = &sWih[row * 32];
            const float* wh = &sWhh[row * 32];
            float4 a0 = *reinterpret_cast<const float4*>(wi + c0);
            float4 a1 = *reinterpret_cast<const float4*>(wi + c1);
            float4 h0v = *reinterpret_cast<const float4*>(wh + c0);
            float4 h1v = *reinterpret_cast<const float4*>(wh + c1);
            float s;
            s = a0.x * xin[0];
            s = fmaf(a0.y, xin[1], s);
            s = fmaf(a0.z, xin[2], s);
            s = fmaf(a0.w, xin[3], s);
            s = fmaf(a1.x, xin[4], s);
            s = fmaf(a1.y, xin[5], s);
            s = fmaf(a1.z, xin[6], s);
            s = fmaf(a1.w, xin[7], s);
            s = fmaf(h0v.x, hin[0], s);
            s = fmaf(h0v.y, hin[1], s);
            s = fmaf(h0v.z, hin[2], s);
            s = fmaf(h0v.w, hin[3], s);
            s = fmaf(h1v.x, hin[4], s);
            s = fmaf(h1v.y, hin[5], s);
            s = fmaf(h1v.z, hin[6], s);
            s = fmaf(h1v.w, hin[7], s);
            P[j] = s;
        }
        return reduceP(P);
    };

    auto gate_dot1 = [&](const float* smat, int gofs, const float (&vin)[8]) -> float {
        float P[4];
        #pragma unroll
        for (int j = 0; j < 4; ++j) {
            const int row = gofs + 4 * p + (j ^ q);
            const int swz = row & 28;
            const int c0 = (8 * q) ^ swz;
            const int c1 = (8 * q + 4) ^ swz;
            const float* wr = &smat[row * 32];
            float4 a0 = *reinterpret_cast<const float4*>(wr + c0);
            float4 a1 = *reinterpret_cast<const float4*>(wr + c1);
            float s;
            s = a0.x * vin[0];
            s = fmaf(a0.y, vin[1], s);
            s = fmaf(a0.z, vin[2], s);
            s = fmaf(a0.w, vin[3], s);
            s = fmaf(a1.x, vin[4], s);
            s = fmaf(a1.y, vin[5], s);
            s = fmaf(a1.z, vin[6], s);
            s = fmaf(a1.w, vin[7], s);
            P[j] = s;
        }
        return reduceP(P);
    };

    // Sequential-gate GRU with sched_barrier fences (pressure insurance)
    auto gru = [&](int t) {
        float xin[8];
        {
            const float* xp = &g_inputs[((size_t)elem * TSTEPS + t) * 32 + 8 * q];
            float4 xa = *reinterpret_cast<const float4*>(xp);
            float4 xb = *reinterpret_cast<const float4*>(xp + 4);
            xin[0] = xa.x; xin[1] = xa.y; xin[2] = xa.z; xin[3] = xa.w;
            xin[4] = xb.x; xin[5] = xb.y; xin[6] = xb.z; xin[7] = xb.w;
        }
        float hin[8];
        gather8(y, hin);
        __builtin_amdgcn_sched_barrier(0);

        float r = sigmf_fast(gate_dot2(0, xin, hin) + br);
        __builtin_amdgcn_sched_barrier(0);
        float z = sigmf_fast(gate_dot2(32, xin, hin) + bz);
        __builtin_amdgcn_sched_barrier(0);
        float nx = gate_dot1(sWih, 64, xin);
        __builtin_amdgcn_sched_barrier(0);
        float nh = gate_dot1(sWhh, 64, hin);
        __builtin_amdgcn_sched_barrier(0);
        float n = tanhf_fast(nx + bin + r * (nh + bhn));
        y = n + z * (y - n);
    };

    // initial integration over [0,1]
    rk4(0.1f);
    #pragma unroll 1
    for (int t = 0; t < TSTEPS - 1; ++t) {
        gru(t);
        rk4(0.1f);
    }
    gru(TSTEPS - 1);
    g_out[(size_t)elem * 32 + cmp] = fmaxf(y, 0.f);              // h_start (relu)
    rk4(1.4f);                                                    // span 14 -> dt 1.4
    g_out[(size_t)BATCH * 32 + (size_t)elem * 32 + cmp] = fmaxf(y, 0.f);  // h_end
}

}  // namespace

extern "C" void kernel_launch(void* const* d_in, const int* in_sizes, int n_in,
                              void* d_out, int out_size, void* d_ws, size_t ws_size,
                              hipStream_t stream) {
    (void)in_sizes; (void)n_in; (void)out_size; (void)d_ws; (void)ws_size;
    const float* inputs = (const float*)d_in[0];
    const float* h0     = (const float*)d_in[1];
    const float* Wih    = (const float*)d_in[2];
    const float* Whh    = (const float*)d_in[3];
    const float* bih    = (const float*)d_in[4];
    const float* bhh    = (const float*)d_in[5];
    const float* W1     = (const float*)d_in[6];
    const float* b1     = (const float*)d_in[7];
    const float* W2     = (const float*)d_in[8];
    const float* b2     = (const float*)d_in[9];
    float* out = (float*)d_out;

    dim3 grid(BATCH / 8);    // 8 elements per 256-thread block (32 lanes/element)
    dim3 block(256);
    hipLaunchKernelGGL(node_kernel, grid, block, 0, stream,
                       inputs, h0, Wih, Whh, bih, bhh, W1, b1, W2, b2, out);
}